// Round 5
// baseline (2532.276 us; speedup 1.0000x reference)
//
#include <hip/hip_runtime.h>
#include <stdint.h>

#define TT 2048
#define BB 128
#define DD 100
#define HH 100
#define GG 300   // 3*H, PyTorch gate order [r,z,n]
#define NT 31
#define NEGV (-10000.0f)

// ---------------------------------------------------------------------------
// Kernel 1: gi[dir][t][g] = x_dir(t) @ w_ih^T + b_ih  for batch row `seq`.
// ---------------------------------------------------------------------------
__global__ __launch_bounds__(320) void gi_kernel(
    const float* __restrict__ sent, const int* __restrict__ seqp,
    const float* __restrict__ w_ih_f, const float* __restrict__ b_ih_f,
    const float* __restrict__ w_ih_b, const float* __restrict__ b_ih_b,
    float* __restrict__ gi)
{
    const int t   = blockIdx.x;
    const int dir = blockIdx.y;
    const int j   = threadIdx.x;
    const int seq = seqp[0];
    const int ts  = dir ? (TT - 1 - t) : t;
    __shared__ __align__(16) float x_s[DD];
    if (j < DD) x_s[j] = sent[((size_t)ts * BB + seq) * DD + j];
    __syncthreads();
    if (j < GG) {
        const float* w = dir ? w_ih_b : w_ih_f;
        const float* b = dir ? b_ih_b : b_ih_f;
        const float4* w4 = (const float4*)(w + j * DD);
        const float4* x4 = (const float4*)x_s;
        float a0 = 0.f, a1 = 0.f, a2 = 0.f, a3 = 0.f;
        #pragma unroll
        for (int k = 0; k < DD / 4; k++) {
            float4 wv = w4[k], xv = x4[k];
            a0 += wv.x * xv.x; a1 += wv.y * xv.y;
            a2 += wv.z * xv.z; a3 += wv.w * xv.w;
        }
        gi[((size_t)dir * TT + t) * GG + j] = b[j] + (a0 + a1) + (a2 + a3);
    }
}

#define RL(v, k) __int_as_float(__builtin_amdgcn_readlane(__float_as_int(v), (k)))

// ---------------------------------------------------------------------------
// Kernel 2: sequential GRU. 512 threads = 8 waves (2/SIMD).
// Wave pair (2q, 2q+1) owns k-quarter q (k in [25q, 25q+25)):
//   wave 2q  ("A"): slot layers 0,2,4  (slots lane, 128+lane, 256+lane)
//   wave 2q+1("B"): slot layers 1,3,5  (slots 64+lane, 192+lane, 320+lane)
// Each lane holds only 3x25 = 75 weight floats -> guaranteed VGPR-resident
// (the R4 structure's 150/lane got demoted; VGPR_Count=96 < weight bytes).
// h[quarter] lives in lanes 0..24 of both waves of the pair; A computes the
// activation and hands h to B through a 25-float LDS buffer (1 write+1 read).
// part layout [q][slot]: write bank = lane%32 -> conflict-free.
// Slots 300..330 are the fused w_out rows; wave 1 sums them into pfeat.
// ---------------------------------------------------------------------------
__global__ __launch_bounds__(512, 2) void gru_seq_kernel(
    const float* __restrict__ gi,
    const float* __restrict__ w_hh_f, const float* __restrict__ b_hh_f,
    const float* __restrict__ w_hh_b, const float* __restrict__ b_hh_b,
    const float* __restrict__ w_out,
    float* __restrict__ pfeat)           // [2][TT][NT], original time order
{
    const int dir  = blockIdx.x;
    const int tid  = threadIdx.x;
    const int wave = tid >> 6, lane = tid & 63;
    const int q    = wave >> 1;
    const bool isA = !(wave & 1);
    const int k0   = q * 25;
    const float* w_hh = dir ? w_hh_b : w_hh_f;
    const float* b_hh = dir ? b_hh_b : b_hh_f;
    const float* gid  = gi + (size_t)dir * TT * GG;
    float* pf = pfeat + (size_t)dir * TT * NT;

    __shared__ float part[2][4][384];    // [buf][quarter][slot]
    __shared__ float hsh[4][32];         // h handoff A -> B per quarter

    // ---- slots & weights (75 floats, named arrays, fully unrolled) ----
    const int s0 = (isA ? 0 : 64) + lane;
    const int s1 = (isA ? 128 : 192) + lane;
    const int s2 = (isA ? 256 : 320) + lane;
    float w0[25], w1[25], w2[25];
    {
        const float* r0 = w_hh + s0 * DD + k0;
        const float* r1 = w_hh + s1 * DD + k0;
        #pragma unroll
        for (int k = 0; k < 25; k++) { w0[k] = r0[k]; w1[k] = r1[k]; }
        if (s2 < GG) {
            const float* r2 = w_hh + s2 * DD + k0;
            #pragma unroll
            for (int k = 0; k < 25; k++) w2[k] = r2[k];
        } else if (s2 < GG + NT) {
            const float* r2 = w_out + (s2 - GG) * (2 * HH) + dir * HH + k0;
            #pragma unroll
            for (int k = 0; k < 25; k++) w2[k] = r2[k];
        } else {
            #pragma unroll
            for (int k = 0; k < 25; k++) w2[k] = 0.f;
        }
    }

    // ---- activation lanes: wave A, lane < 25, row r = q*25 + lane ----
    const bool is_act = isA && (lane < 25);
    const int  r      = k0 + lane;
    float bhr = 0.f, bhz = 0.f, bhn = 0.f;
    if (is_act) { bhr = b_hh[r]; bhz = b_hh[HH + r]; bhn = b_hh[2 * HH + r]; }

    // ---- pfeat lanes: wave 1, lanes 32..62 -> p = lane-32 ----
    const int  p     = lane - 32;
    const bool is_pf = (wave == 1) && (p >= 0) && (p < NT);
    float pf_hist[8];

    float hreg = 0.f;                    // lane L<25: h[k0+L]

    // gi prefetch pipeline depth 2 (act lanes only)
    float gAr = 0.f, gAz = 0.f, gAn = 0.f, gBr = 0.f, gBz = 0.f, gBn = 0.f;
    if (is_act) {
        gAr = gid[r]; gAz = gid[HH + r]; gAn = gid[2 * HH + r];
        gBr = gid[GG + r]; gBz = gid[GG + HH + r]; gBn = gid[GG + 2 * HH + r];
    }
    __syncthreads();

    auto do_step = [&](int t, float& cr, float& cz, float& cn) {
        const int buf = t & 1;
        // ---- dot phase: 25 readlanes, 3 FMAs each ----
        float a0 = 0.f, a1 = 0.f, a2 = 0.f;
        #pragma unroll
        for (int k = 0; k < 25; k++) {
            float hk = RL(hreg, k);
            a0 = fmaf(hk, w0[k], a0);
            a1 = fmaf(hk, w1[k], a1);
            a2 = fmaf(hk, w2[k], a2);
        }
        part[buf][q][s0] = a0;
        part[buf][q][s1] = a1;
        part[buf][q][s2] = a2;
        __syncthreads();                               // b1: partials ready
        if (is_act) {
            float pr = part[buf][0][r]      + part[buf][1][r]
                     + part[buf][2][r]      + part[buf][3][r];
            float pz = part[buf][0][HH + r] + part[buf][1][HH + r]
                     + part[buf][2][HH + r] + part[buf][3][HH + r];
            float pn = part[buf][0][2*HH+r] + part[buf][1][2*HH+r]
                     + part[buf][2][2*HH+r] + part[buf][3][2*HH+r];
            float xr  = pr + bhr + cr;
            float xz  = pz + bhz + cz;
            float ghn = pn + bhn;
            float rr  = 1.f / (1.f + __expf(-xr));
            float zz  = 1.f / (1.f + __expf(-xz));
            float pre = cn + rr * ghn;
            pre = fmaxf(fminf(pre, 40.f), -40.f);
            float e2  = __expf(-2.f * pre);
            float nn  = (1.f - e2) / (1.f + e2);
            float hv  = (1.f - zz) * nn + zz * hreg;
            hsh[q][lane] = hv;
            hreg = hv;
            int tp = t + 2; tp = (tp < TT) ? tp : (TT - 1);   // prefetch gi
            cr = gid[tp * GG + r];
            cz = gid[tp * GG + HH + r];
            cn = gid[tp * GG + 2 * HH + r];
        }
        if (is_pf && t > 0) {                          // feat of time t-1
            float f = part[buf][0][GG + p] + part[buf][1][GG + p]
                    + part[buf][2][GG + p] + part[buf][3][GG + p];
            pf_hist[(t - 1) & 7] = f;
        }
        if (is_pf && t >= 8 && (t & 7) == 0) {         // flush times t-8..t-1
            int tb = t - 8;
            #pragma unroll
            for (int i = 0; i < 8; i++) {
                int tm = tb + i;
                int ot = dir ? (TT - 1 - tm) : tm;
                pf[(size_t)ot * NT + p] = pf_hist[i];
            }
        }
        __syncthreads();                               // b2: h handoff ready
        if (!isA && lane < 25) hreg = hsh[q][lane];
    };

    for (int t = 0; t < TT; t += 2) {
        do_step(t,     gAr, gAz, gAn);
        do_step(t + 1, gBr, gBz, gBn);
    }

    // ---- epilogue: feat of time TT-1 from h_{TT-1} ----
    {
        float a2 = 0.f;
        #pragma unroll
        for (int k = 0; k < 25; k++) a2 = fmaf(RL(hreg, k), w2[k], a2);
        part[0][q][s2] = a2;
        __syncthreads();
        if (is_pf) {
            float f = part[0][0][GG + p] + part[0][1][GG + p]
                    + part[0][2][GG + p] + part[0][3][GG + p];
            pf_hist[7] = f;                            // (TT-1)&7 == 7
            int tb = TT - 8;
            #pragma unroll
            for (int i = 0; i < 8; i++) {
                int tm = tb + i;
                int ot = dir ? (TT - 1 - tm) : tm;
                pf[(size_t)ot * NT + p] = pf_hist[i];
            }
        }
    }
}

// ---------------------------------------------------------------------------
// Kernel 3a: serial Viterbi fv scan (values only; max is order-exact).
// Single wave, zero barriers, feats prefetched 8 deep. fvg[t] = fv BEFORE
// step t (slot 0 = init).
// ---------------------------------------------------------------------------
__global__ __launch_bounds__(64) void vit_scan_kernel(
    const float* __restrict__ pfeat, const float* __restrict__ mask,
    const int* __restrict__ seqp, const float* __restrict__ trans,
    const float* __restrict__ b_out,
    float* __restrict__ fvg, int* __restrict__ meta, float* __restrict__ out)
{
    const int lane = threadIdx.x;
    const int ln   = (lane < NT) ? lane : (NT - 1);   // clamped for loads
    const float* mrow = mask + (size_t)seqp[0] * TT;
    const float* pff = pfeat;
    const float* pfb = pfeat + (size_t)TT * NT;

    float trp[NT];
    #pragma unroll
    for (int q = 0; q < NT; q++) trp[q] = trans[ln * NT + q];
    const float bo = b_out[ln];

    float fv = (lane == 0) ? 0.f : NEGV;
    fvg[lane] = fv;                                   // slot 0 = init

    float ffr[8], fbr[8], mr[8];
    #pragma unroll
    for (int q = 0; q < 8; q++) {
        ffr[q] = pff[q * NT + ln]; fbr[q] = pfb[q * NT + ln]; mr[q] = mrow[q];
    }

    for (int t = 0; t < TT; t += 8) {
        #pragma unroll
        for (int q = 0; q < 8; q++) {
            float fcur = ffr[q] + fbr[q] + bo;
            float mcur = mr[q];
            int tp = t + q + 8; tp = (tp < TT) ? tp : (TT - 1);
            ffr[q] = pff[tp * NT + ln]; fbr[q] = pfb[tp * NT + ln]; mr[q] = mrow[tp];
            float v[NT];
            #pragma unroll
            for (int q2 = 0; q2 < NT; q2++) v[q2] = RL(fv, q2) + trp[q2];
            float m = v[0];
            #pragma unroll
            for (int q2 = 1; q2 + 1 < NT; q2 += 2)
                m = fmaxf(fmaxf(m, v[q2]), v[q2 + 1]);   // -> v_max3
            float cand = m + fcur;
            fv = (mcur > 0.f) ? cand : fv;
            fvg[(t + q + 1) * 64 + lane] = fv;
        }
    }

    // final argmax, strict '>' ascending = first-max
    float fbest = RL(fv, 0);
    int ftag = 0;
    #pragma unroll
    for (int q = 1; q < NT; q++) {
        float s = RL(fv, q);
        if (s > fbest) { fbest = s; ftag = q; }
    }
    if (lane == 0) { out[0] = fbest; meta[0] = ftag; }
}

// ---------------------------------------------------------------------------
// Kernel 3b: parallel backpointer pass. Block b: t in [64b, 64b+64), 16 waves
// x 4 t's each. Recomputes argmax from stored fv (bit-exact same operands),
// exact first-max; wave 0 composes the block's 64 backpointer maps.
// ---------------------------------------------------------------------------
__global__ __launch_bounds__(1024) void vit_bp_kernel(
    const float* __restrict__ fvg, const float* __restrict__ mask,
    const int* __restrict__ seqp, const float* __restrict__ trans,
    uint8_t* __restrict__ bpg, uint8_t* __restrict__ gmapg)
{
    const int b    = blockIdx.x;
    const int tid  = threadIdx.x;
    const int wave = tid >> 6, lane = tid & 63;
    const int j    = lane & 31;
    const int jr   = (j < NT) ? j : (NT - 1);
    const float* mrow = mask + (size_t)seqp[0] * TT;

    __shared__ int bpl[64][32];

    float trj[NT];
    #pragma unroll
    for (int q = 0; q < NT; q++) trj[q] = trans[jr * NT + q];

    #pragma unroll
    for (int q4 = 0; q4 < 4; q4++) {
        const int t = b * 64 + wave * 4 + q4;
        float fvp = fvg[t * 64 + lane];          // lane p holds fv_prev[p]
        float mcur = mrow[t];
        float best = RL(fvp, 0) + trj[0];
        int bi = 0;
        #pragma unroll
        for (int q = 1; q < NT; q++) {
            float s = RL(fvp, q) + trj[q];
            if (s > best) { best = s; bi = q; }  // ascending strict '>' = first-max
        }
        int bpn = (mcur > 0.f) ? bi : j;
        if (j == 31) bpn = 31;
        if (lane < 32) {
            bpl[wave * 4 + q4][lane] = bpn;
            if (j < NT) bpg[(size_t)t * NT + j] = (uint8_t)bpn;
        }
    }
    __syncthreads();
    if (wave == 0) {
        int G = j;
        for (int i = 0; i < 64; i++) {
            int bpv = bpl[i][j];
            G = __shfl(G, bpv);                  // G_new[j] = G_old[bp_i[j]]
        }
        if (lane < 32) gmapg[b * 32 + lane] = (uint8_t)G;
    }
}

// ---------------------------------------------------------------------------
// Kernel 3c: backtrack. Loads all backpointers into LDS, composes the 32
// block maps serially (lane 0), then 32 lanes backtrack 64 steps each.
// ---------------------------------------------------------------------------
__global__ __launch_bounds__(64) void vit_back_kernel(
    const uint8_t* __restrict__ bpg, const uint8_t* __restrict__ gmapg,
    const int* __restrict__ meta, float* __restrict__ out)
{
    const int tid = threadIdx.x;
    __shared__ uint8_t bps[TT * NT];     // 63488 B
    __shared__ uint8_t gm[32 * 32];
    __shared__ uint8_t echk[32];

    const uint32_t* src = (const uint32_t*)bpg;
    uint32_t* dst = (uint32_t*)bps;
    for (int i = tid; i < TT * NT / 4; i += 64) dst[i] = src[i];
    for (int i = tid; i < 1024 / 4; i += 64)
        ((uint32_t*)gm)[i] = ((const uint32_t*)gmapg)[i];
    __syncthreads();

    if (tid == 0) {
        int tag = meta[0];
        for (int b = 31; b >= 0; b--) { echk[b] = (uint8_t)tag; tag = gm[b * 32 + tag]; }
    }
    __syncthreads();
    if (tid < 32) {
        int tag = echk[tid];
        for (int i = 63; i >= 0; i--) {
            int t = tid * 64 + i;
            out[1 + t] = (float)tag;
            tag = bps[t * NT + tag];
        }
    }
}

// ---------------------------------------------------------------------------
extern "C" void kernel_launch(void* const* d_in, const int* in_sizes, int n_in,
                              void* d_out, int out_size, void* d_ws, size_t ws_size,
                              hipStream_t stream) {
    const float* sent   = (const float*)d_in[0];
    const float* mask   = (const float*)d_in[1];
    const float* w_ih_f = (const float*)d_in[2];
    const float* w_hh_f = (const float*)d_in[3];
    const float* b_ih_f = (const float*)d_in[4];
    const float* b_hh_f = (const float*)d_in[5];
    const float* w_ih_b = (const float*)d_in[6];
    const float* w_hh_b = (const float*)d_in[7];
    const float* b_ih_b = (const float*)d_in[8];
    const float* b_hh_b = (const float*)d_in[9];
    const float* w_out  = (const float*)d_in[10];
    const float* b_out  = (const float*)d_in[11];
    const float* trans  = (const float*)d_in[12];
    const int*   seqp   = (const int*)d_in[14];
    float* out = (float*)d_out;

    // ws layout (floats): gi[2*TT*300] | pfeat[2*TT*31] | fvg[(TT+1)*64] |
    //                     bpg (TT*31 bytes) | gmapg (1024 bytes) | meta
    float* gi    = (float*)d_ws;
    float* pfeat = gi + (size_t)2 * TT * GG;
    float* fvg   = pfeat + (size_t)2 * TT * NT;
    float* bpf   = fvg + (size_t)(TT + 1) * 64;
    uint8_t* bpg   = (uint8_t*)bpf;
    uint8_t* gmapg = bpg + (size_t)TT * NT;
    int*     meta  = (int*)(gmapg + 1024);

    gi_kernel<<<dim3(TT, 2), 320, 0, stream>>>(sent, seqp, w_ih_f, b_ih_f,
                                               w_ih_b, b_ih_b, gi);
    gru_seq_kernel<<<2, 512, 0, stream>>>(gi, w_hh_f, b_hh_f, w_hh_b, b_hh_b,
                                          w_out, pfeat);
    vit_scan_kernel<<<1, 64, 0, stream>>>(pfeat, mask, seqp, trans, b_out,
                                          fvg, meta, out);
    vit_bp_kernel<<<32, 1024, 0, stream>>>(fvg, mask, seqp, trans, bpg, gmapg);
    vit_back_kernel<<<1, 64, 0, stream>>>(bpg, gmapg, meta, out);
}

// Round 6
// 2188.731 us; speedup vs baseline: 1.1570x; 1.1570x over previous
//
#include <hip/hip_runtime.h>
#include <stdint.h>

#define TT 2048
#define BB 128
#define DD 100
#define HH 100
#define GG 300   // 3*H, PyTorch gate order [r,z,n]
#define NT 31
#define NEGV (-10000.0f)

#define REP25(M) M(0) M(1) M(2) M(3) M(4) M(5) M(6) M(7) M(8) M(9) M(10) M(11) \
                 M(12) M(13) M(14) M(15) M(16) M(17) M(18) M(19) M(20) M(21) M(22) M(23) M(24)
#define REP31(M) M(0) M(1) M(2) M(3) M(4) M(5) M(6) M(7) M(8) M(9) M(10) M(11) \
                 M(12) M(13) M(14) M(15) M(16) M(17) M(18) M(19) M(20) M(21) M(22) M(23) \
                 M(24) M(25) M(26) M(27) M(28) M(29) M(30)
#define REP8(M)  M(0) M(1) M(2) M(3) M(4) M(5) M(6) M(7)

#define RL(v, k) __int_as_float(__builtin_amdgcn_readlane(__float_as_int(v), (k)))

// ---------------------------------------------------------------------------
// Kernel 1: gi[dir][t][g] = x_dir(t) @ w_ih^T + b_ih  for batch row `seq`.
// ---------------------------------------------------------------------------
__global__ __launch_bounds__(320) void gi_kernel(
    const float* __restrict__ sent, const int* __restrict__ seqp,
    const float* __restrict__ w_ih_f, const float* __restrict__ b_ih_f,
    const float* __restrict__ w_ih_b, const float* __restrict__ b_ih_b,
    float* __restrict__ gi)
{
    const int t   = blockIdx.x;
    const int dir = blockIdx.y;
    const int j   = threadIdx.x;
    const int seq = seqp[0];
    const int ts  = dir ? (TT - 1 - t) : t;
    __shared__ __align__(16) float x_s[DD];
    if (j < DD) x_s[j] = sent[((size_t)ts * BB + seq) * DD + j];
    __syncthreads();
    if (j < GG) {
        const float* w = dir ? w_ih_b : w_ih_f;
        const float* b = dir ? b_ih_b : b_ih_f;
        const float4* w4 = (const float4*)(w + j * DD);
        const float4* x4 = (const float4*)x_s;
        float a0 = 0.f, a1 = 0.f, a2 = 0.f, a3 = 0.f;
        #pragma unroll
        for (int k = 0; k < DD / 4; k++) {
            float4 wv = w4[k], xv = x4[k];
            a0 += wv.x * xv.x; a1 += wv.y * xv.y;
            a2 += wv.z * xv.z; a3 += wv.w * xv.w;
        }
        gi[((size_t)dir * TT + t) * GG + j] = b[j] + (a0 + a1) + (a2 + a3);
    }
}

// ---------------------------------------------------------------------------
// Kernel 2: sequential GRU. 512 threads = 8 waves (2/SIMD).
// Wave pair (2q, 2q+1) owns k-quarter q (k in [25q, 25q+25)).
//   wave 2q  ("A"): slots lane, 128+lane, 256+lane
//   wave 2q+1("B"): slots 64+lane, 192+lane, 320+lane
// Weights are 75 NAMED SCALARS per lane (macro-generated): the compiler's
// promote-alloca pass refused to register-promote weight ARRAYS in R2-R5
// (VGPR_Count 64..124 < weight bytes => scratch spill was the bottleneck).
// Both waves of a pair compute the activation redundantly from the shared
// LDS partials -> ONE barrier per step (ping-pong part buffers).
// Slots 300..330 = fused w_out rows; wave 1 lanes 32..62 sum them to pfeat.
// ---------------------------------------------------------------------------
__global__ __launch_bounds__(512, 2) void gru_seq_kernel(
    const float* __restrict__ gi,
    const float* __restrict__ w_hh_f, const float* __restrict__ b_hh_f,
    const float* __restrict__ w_hh_b, const float* __restrict__ b_hh_b,
    const float* __restrict__ w_out,
    float* __restrict__ pfeat)           // [2][TT][NT], original time order
{
    const int dir  = blockIdx.x;
    const int tid  = threadIdx.x;
    const int wave = tid >> 6, lane = tid & 63;
    const int q    = wave >> 1;
    const bool isA = !(wave & 1);
    const int k0   = q * 25;
    const float* w_hh = dir ? w_hh_b : w_hh_f;
    const float* b_hh = dir ? b_hh_b : b_hh_f;
    const float* gid  = gi + (size_t)dir * TT * GG;
    float* pf = pfeat + (size_t)dir * TT * NT;

    __shared__ float part[2][4][384];    // [buf][quarter][slot]

    const int s0 = (isA ? 0 : 64) + lane;
    const int s1 = (isA ? 128 : 192) + lane;
    const int s2 = (isA ? 256 : 320) + lane;

    const float* r0 = w_hh + s0 * DD + k0;
    const float* r1 = w_hh + s1 * DD + k0;
    // dead slots (>=331) read w_out row 30 harmlessly; their partials land in
    // unused part slots.
    const int wrow = (s2 - GG) < (NT - 1) ? (s2 - GG) : (NT - 1);
    const float* r2 = (s2 < GG) ? (w_hh + s2 * DD + k0)
                                : (w_out + wrow * (2 * HH) + dir * HH + k0);

    // ---- 75 named-scalar weights ----
    #define DECLW(i) float w0_##i, w1_##i, w2_##i;
    REP25(DECLW)
    #define LDW(i) w0_##i = r0[i]; w1_##i = r1[i]; w2_##i = r2[i];
    REP25(LDW)

    // ---- activation lanes: lane < 25 in EVERY wave, row r = k0 + lane ----
    const int r = k0 + lane;
    float bhr = 0.f, bhz = 0.f, bhn = 0.f;
    if (lane < 25) { bhr = b_hh[r]; bhz = b_hh[HH + r]; bhn = b_hh[2 * HH + r]; }

    // ---- pfeat lanes: wave 1, lanes 32..62 -> p = lane-32 ----
    const int  p     = lane - 32;
    const bool is_pf = (wave == 1) && (p >= 0) && (p < NT);
    #define DECLPH(i) float ph##i = 0.f;
    REP8(DECLPH)

    float hreg = 0.f;                    // lane L<25: h[k0+L]

    // gi prefetch pipeline depth 2 (act lanes only)
    float gAr = 0.f, gAz = 0.f, gAn = 0.f, gBr = 0.f, gBz = 0.f, gBn = 0.f;
    if (lane < 25) {
        gAr = gid[r];      gAz = gid[HH + r];      gAn = gid[2 * HH + r];
        gBr = gid[GG + r]; gBz = gid[GG + HH + r]; gBn = gid[GG + 2 * HH + r];
    }

    #define DOTK(i) { float hk = RL(hreg, i);              \
        a0 = fmaf(hk, w0_##i, a0);                          \
        a1 = fmaf(hk, w1_##i, a1);                          \
        a2 = fmaf(hk, w2_##i, a2); }

    #define GRU_STEP(TIDX, BUF, SLOT, cr, cz, cn) {                          \
        float a0 = 0.f, a1 = 0.f, a2 = 0.f;                                  \
        REP25(DOTK)                                                          \
        part[BUF][q][s0] = a0;                                               \
        part[BUF][q][s1] = a1;                                               \
        part[BUF][q][s2] = a2;                                               \
        __syncthreads();                                                     \
        if (lane < 25) {                                                     \
            float pr = part[BUF][0][r] + part[BUF][1][r]                     \
                     + part[BUF][2][r] + part[BUF][3][r];                    \
            float pz = part[BUF][0][HH + r] + part[BUF][1][HH + r]           \
                     + part[BUF][2][HH + r] + part[BUF][3][HH + r];          \
            float pn = part[BUF][0][2 * HH + r] + part[BUF][1][2 * HH + r]   \
                     + part[BUF][2][2 * HH + r] + part[BUF][3][2 * HH + r];  \
            float xr  = pr + bhr + (cr);                                     \
            float xz  = pz + bhz + (cz);                                     \
            float ghn = pn + bhn;                                            \
            float rr  = 1.f / (1.f + __expf(-xr));                           \
            float zz  = 1.f / (1.f + __expf(-xz));                           \
            float pre = (cn) + rr * ghn;                                     \
            pre = fmaxf(fminf(pre, 40.f), -40.f);                            \
            float e2  = __expf(-2.f * pre);                                  \
            float nn  = (1.f - e2) / (1.f + e2);                             \
            hreg = (1.f - zz) * nn + zz * hreg;                              \
            int tp = (TIDX) + 2; tp = (tp < TT) ? tp : (TT - 1);             \
            cr = gid[tp * GG + r];                                           \
            cz = gid[tp * GG + HH + r];                                      \
            cn = gid[tp * GG + 2 * HH + r];                                  \
        }                                                                    \
        if (is_pf && (TIDX) > 0) {                                           \
            ph##SLOT = part[BUF][0][GG + p] + part[BUF][1][GG + p]           \
                     + part[BUF][2][GG + p] + part[BUF][3][GG + p];          \
        }                                                                    \
    }

    #define PHST(i) pf[(size_t)(dir ? (TT - 1 - (tb + i)) : (tb + i)) * NT + p] = ph##i;

    for (int tt = 0; tt < TT; tt += 8) {
        GRU_STEP(tt + 0, 0, 7, gAr, gAz, gAn)
        if (is_pf && tt >= 8) { int tb = tt - 8; REP8(PHST) }
        GRU_STEP(tt + 1, 1, 0, gBr, gBz, gBn)
        GRU_STEP(tt + 2, 0, 1, gAr, gAz, gAn)
        GRU_STEP(tt + 3, 1, 2, gBr, gBz, gBn)
        GRU_STEP(tt + 4, 0, 3, gAr, gAz, gAn)
        GRU_STEP(tt + 5, 1, 4, gBr, gBz, gBn)
        GRU_STEP(tt + 6, 0, 5, gAr, gAz, gAn)
        GRU_STEP(tt + 7, 1, 6, gBr, gBz, gBn)
    }

    // ---- epilogue: feat of time TT-1 from final h ----
    {
        float a2 = 0.f;
        #define DOT2K(i) a2 = fmaf(RL(hreg, i), w2_##i, a2);
        REP25(DOT2K)
        part[0][q][s2] = a2;
        __syncthreads();
        if (is_pf) {
            ph7 = part[0][0][GG + p] + part[0][1][GG + p]
                + part[0][2][GG + p] + part[0][3][GG + p];
            int tb = TT - 8;
            REP8(PHST)
        }
    }
}

// ---------------------------------------------------------------------------
// Kernel 3a: serial Viterbi fv scan (values only; max is order-exact).
// Single wave, zero barriers, tree-max (depth 5), trans row in named scalars.
// fvg[t] = fv BEFORE step t (slot 0 = init).
// ---------------------------------------------------------------------------
__global__ __launch_bounds__(64) void vit_scan_kernel(
    const float* __restrict__ pfeat, const float* __restrict__ mask,
    const int* __restrict__ seqp, const float* __restrict__ trans,
    const float* __restrict__ b_out,
    float* __restrict__ fvg, int* __restrict__ meta, float* __restrict__ out)
{
    const int lane = threadIdx.x;
    const int ln   = (lane < NT) ? lane : (NT - 1);   // clamped for loads
    const float* mrow = mask + (size_t)seqp[0] * TT;
    const float* pff = pfeat;
    const float* pfb = pfeat + (size_t)TT * NT;

    #define DECLTR(i) float tr##i = trans[ln * NT + i];
    REP31(DECLTR)
    const float bo = b_out[ln];

    float fv = (lane == 0) ? 0.f : NEGV;
    fvg[lane] = fv;                                   // slot 0 = init

    float ffr[8], fbr[8], mr[8];
    #pragma unroll
    for (int q = 0; q < 8; q++) {
        ffr[q] = pff[q * NT + ln]; fbr[q] = pfb[q * NT + ln]; mr[q] = mrow[q];
    }

    for (int t = 0; t < TT; t += 8) {
        #pragma unroll
        for (int q = 0; q < 8; q++) {
            float fcur = ffr[q] + fbr[q] + bo;
            float mcur = mr[q];
            int tp = t + q + 8; tp = (tp < TT) ? tp : (TT - 1);
            ffr[q] = pff[tp * NT + ln]; fbr[q] = pfb[tp * NT + ln]; mr[q] = mrow[tp];
            #define VADD(i) float v##i = RL(fv, i) + tr##i;
            REP31(VADD)
            #undef VADD
            // depth-5 max tree
            v0  = fmaxf(v0,  v16); v1  = fmaxf(v1,  v17); v2  = fmaxf(v2,  v18);
            v3  = fmaxf(v3,  v19); v4  = fmaxf(v4,  v20); v5  = fmaxf(v5,  v21);
            v6  = fmaxf(v6,  v22); v7  = fmaxf(v7,  v23); v8  = fmaxf(v8,  v24);
            v9  = fmaxf(v9,  v25); v10 = fmaxf(v10, v26); v11 = fmaxf(v11, v27);
            v12 = fmaxf(v12, v28); v13 = fmaxf(v13, v29); v14 = fmaxf(v14, v30);
            v0 = fmaxf(v0, v8);  v1 = fmaxf(v1, v9);  v2 = fmaxf(v2, v10);
            v3 = fmaxf(v3, v11); v4 = fmaxf(v4, v12); v5 = fmaxf(v5, v13);
            v6 = fmaxf(v6, v14); v7 = fmaxf(v7, v15);
            v0 = fmaxf(v0, v4); v1 = fmaxf(v1, v5); v2 = fmaxf(v2, v6); v3 = fmaxf(v3, v7);
            v0 = fmaxf(v0, v2); v1 = fmaxf(v1, v3);
            float m = fmaxf(v0, v1);
            float cand = m + fcur;
            fv = (mcur > 0.f) ? cand : fv;
            fvg[(t + q + 1) * 64 + lane] = fv;
        }
    }

    // final argmax, strict '>' ascending = first-max
    float fbest = RL(fv, 0);
    int ftag = 0;
    #pragma unroll
    for (int q = 1; q < NT; q++) {
        float s = RL(fv, q);
        if (s > fbest) { fbest = s; ftag = q; }
    }
    if (lane == 0) { out[0] = fbest; meta[0] = ftag; }
}

// ---------------------------------------------------------------------------
// Kernel 3b: parallel backpointer pass. Block b: t in [64b, 64b+64), 16 waves
// x 4 t's each. Recomputes argmax from stored fv (bit-exact same operands),
// exact first-max; wave 0 composes the block's 64 backpointer maps.
// ---------------------------------------------------------------------------
__global__ __launch_bounds__(1024) void vit_bp_kernel(
    const float* __restrict__ fvg, const float* __restrict__ mask,
    const int* __restrict__ seqp, const float* __restrict__ trans,
    uint8_t* __restrict__ bpg, uint8_t* __restrict__ gmapg)
{
    const int b    = blockIdx.x;
    const int tid  = threadIdx.x;
    const int wave = tid >> 6, lane = tid & 63;
    const int j    = lane & 31;
    const int jr   = (j < NT) ? j : (NT - 1);
    const float* mrow = mask + (size_t)seqp[0] * TT;

    __shared__ int bpl[64][32];

    float trj[NT];
    #pragma unroll
    for (int q = 0; q < NT; q++) trj[q] = trans[jr * NT + q];

    #pragma unroll
    for (int q4 = 0; q4 < 4; q4++) {
        const int t = b * 64 + wave * 4 + q4;
        float fvp = fvg[t * 64 + lane];          // lane p holds fv_prev[p]
        float mcur = mrow[t];
        float best = RL(fvp, 0) + trj[0];
        int bi = 0;
        #pragma unroll
        for (int q = 1; q < NT; q++) {
            float s = RL(fvp, q) + trj[q];
            if (s > best) { best = s; bi = q; }  // ascending strict '>' = first-max
        }
        int bpn = (mcur > 0.f) ? bi : j;
        if (j == 31) bpn = 31;
        if (lane < 32) {
            bpl[wave * 4 + q4][lane] = bpn;
            if (j < NT) bpg[(size_t)t * NT + j] = (uint8_t)bpn;
        }
    }
    __syncthreads();
    if (wave == 0) {
        int G = j;
        for (int i = 0; i < 64; i++) {
            int bpv = bpl[i][j];
            G = __shfl(G, bpv);                  // G_new[j] = G_old[bp_i[j]]
        }
        if (lane < 32) gmapg[b * 32 + lane] = (uint8_t)G;
    }
}

// ---------------------------------------------------------------------------
// Kernel 3c: backtrack. Loads all backpointers into LDS, composes the 32
// block maps serially (lane 0), then 32 lanes backtrack 64 steps each.
// ---------------------------------------------------------------------------
__global__ __launch_bounds__(64) void vit_back_kernel(
    const uint8_t* __restrict__ bpg, const uint8_t* __restrict__ gmapg,
    const int* __restrict__ meta, float* __restrict__ out)
{
    const int tid = threadIdx.x;
    __shared__ uint8_t bps[TT * NT];     // 63488 B
    __shared__ uint8_t gm[32 * 32];
    __shared__ uint8_t echk[32];

    const uint32_t* src = (const uint32_t*)bpg;
    uint32_t* dst = (uint32_t*)bps;
    for (int i = tid; i < TT * NT / 4; i += 64) dst[i] = src[i];
    for (int i = tid; i < 1024 / 4; i += 64)
        ((uint32_t*)gm)[i] = ((const uint32_t*)gmapg)[i];
    __syncthreads();

    if (tid == 0) {
        int tag = meta[0];
        for (int b = 31; b >= 0; b--) { echk[b] = (uint8_t)tag; tag = gm[b * 32 + tag]; }
    }
    __syncthreads();
    if (tid < 32) {
        int tag = echk[tid];
        for (int i = 63; i >= 0; i--) {
            int t = tid * 64 + i;
            out[1 + t] = (float)tag;
            tag = bps[t * NT + tag];
        }
    }
}

// ---------------------------------------------------------------------------
extern "C" void kernel_launch(void* const* d_in, const int* in_sizes, int n_in,
                              void* d_out, int out_size, void* d_ws, size_t ws_size,
                              hipStream_t stream) {
    const float* sent   = (const float*)d_in[0];
    const float* mask   = (const float*)d_in[1];
    const float* w_ih_f = (const float*)d_in[2];
    const float* w_hh_f = (const float*)d_in[3];
    const float* b_ih_f = (const float*)d_in[4];
    const float* b_hh_f = (const float*)d_in[5];
    const float* w_ih_b = (const float*)d_in[6];
    const float* w_hh_b = (const float*)d_in[7];
    const float* b_ih_b = (const float*)d_in[8];
    const float* b_hh_b = (const float*)d_in[9];
    const float* w_out  = (const float*)d_in[10];
    const float* b_out  = (const float*)d_in[11];
    const float* trans  = (const float*)d_in[12];
    const int*   seqp   = (const int*)d_in[14];
    float* out = (float*)d_out;

    // ws layout (floats): gi[2*TT*300] | pfeat[2*TT*31] | fvg[(TT+1)*64] |
    //                     bpg (TT*31 bytes) | gmapg (1024 bytes) | meta
    float* gi    = (float*)d_ws;
    float* pfeat = gi + (size_t)2 * TT * GG;
    float* fvg   = pfeat + (size_t)2 * TT * NT;
    float* bpf   = fvg + (size_t)(TT + 1) * 64;
    uint8_t* bpg   = (uint8_t*)bpf;
    uint8_t* gmapg = bpg + (size_t)TT * NT;
    int*     meta  = (int*)(gmapg + 1024);

    gi_kernel<<<dim3(TT, 2), 320, 0, stream>>>(sent, seqp, w_ih_f, b_ih_f,
                                               w_ih_b, b_ih_b, gi);
    gru_seq_kernel<<<2, 512, 0, stream>>>(gi, w_hh_f, b_hh_f, w_hh_b, b_hh_b,
                                          w_out, pfeat);
    vit_scan_kernel<<<1, 64, 0, stream>>>(pfeat, mask, seqp, trans, b_out,
                                          fvg, meta, out);
    vit_bp_kernel<<<32, 1024, 0, stream>>>(fvg, mask, seqp, trans, bpg, gmapg);
    vit_back_kernel<<<1, 64, 0, stream>>>(bpg, gmapg, meta, out);
}